// Round 13
// baseline (4130.658 us; speedup 1.0000x reference)
//
#include <hip/hip_runtime.h>

// ---------------------------------------------------------------------------
// miniGPT forward: 4 layers, D=768, H=12, HID=3072, V=32000, B=4, S=1024
// Round 13: gemm8p BK 64->32 (same 256x256 tile / arithmetic intensity),
// LDS 2x32KB -> 2 blocks/CU TLP to cover fetch stalls. Everything else as
// round 12 (noise-equivalent champion).
// ---------------------------------------------------------------------------

typedef __bf16 bf16_t;
typedef bf16_t bf16x8 __attribute__((ext_vector_type(8)));
typedef bf16_t bf16x4 __attribute__((ext_vector_type(4)));
typedef float f32x4 __attribute__((ext_vector_type(4)));

#define GLD16(G, L) __builtin_amdgcn_global_load_lds(                          \
    (const __attribute__((address_space(1))) unsigned int*)(const void*)(G),   \
    (__attribute__((address_space(3))) unsigned int*)(void*)(L), 16, 0, 0)

__device__ __forceinline__ f32x4 mfma16(bf16x8 a, bf16x8 b, f32x4 c) {
  return __builtin_amdgcn_mfma_f32_16x16x32_bf16(a, b, c, 0, 0, 0);
}

__device__ __forceinline__ void barrier_raw() {
  asm volatile("s_barrier" ::: "memory");
}

__device__ __forceinline__ void lgkm0() {
  asm volatile("s_waitcnt lgkmcnt(0)" ::: "memory");
}

#define RED16_MAX(x) { x = fmaxf(x, __shfl_xor(x, 1)); x = fmaxf(x, __shfl_xor(x, 2)); \
                       x = fmaxf(x, __shfl_xor(x, 4)); x = fmaxf(x, __shfl_xor(x, 8)); }
#define RED16_SUM(x) { x += __shfl_xor(x, 1); x += __shfl_xor(x, 2); \
                       x += __shfl_xor(x, 4); x += __shfl_xor(x, 8); }

__device__ __forceinline__ int SW64(int row, int col) {
  return row * 64 + (col ^ ((row & 7) << 3));
}

// ---------------- transpose + f32->bf16 convert: in[K][N] -> out[N][K] ------
__global__ __launch_bounds__(256)
void tconv_k(const float* __restrict__ in, bf16_t* __restrict__ out, int K, int N,
             size_t in_ls, size_t out_ls) {
  __shared__ float tile[32][33];
  in  += (size_t)blockIdx.z * in_ls;
  out += (size_t)blockIdx.z * out_ls;
  const int n0 = blockIdx.x * 32, k0 = blockIdx.y * 32;
  const int tx = threadIdx.x & 31, ty = threadIdx.x >> 5;
#pragma unroll
  for (int j = 0; j < 4; ++j)
    tile[ty + j * 8][tx] = in[(size_t)(k0 + ty + j * 8) * N + n0 + tx];
  __syncthreads();
#pragma unroll
  for (int j = 0; j < 4; ++j)
    out[(size_t)(n0 + ty + j * 8) * K + k0 + tx] = (bf16_t)tile[tx][ty + j * 8];
}

// ---------------- concat q/k/v biases per layer -> [L][2304] ----------------
__global__ void qkvbias_k(const float* __restrict__ bq, const float* __restrict__ bk,
                          const float* __restrict__ bv, float* __restrict__ out) {
  const int l = blockIdx.x;
  for (int j = threadIdx.x; j < 2304; j += 256) {
    float v = (j < 768) ? bq[l * 768 + j]
            : (j < 1536) ? bk[l * 768 + j - 768]
                         : bv[l * 768 + j - 1536];
    out[l * 2304 + j] = v;
  }
}

// ---------------- embedding + positional encoding ---------------------------
__global__ __launch_bounds__(256)
void embed_k(const int* __restrict__ tok, const float* __restrict__ emb,
             const float* __restrict__ pe, float* __restrict__ xf) {
  const int row = blockIdx.x, tid = threadIdx.x;
  const int s = row & 1023;
  const int t = tok[row];
  float* o = xf + (size_t)row * 768;
  const float* e = emb + (size_t)t * 768;
  const float* p = pe + (size_t)s * 768;
  o[tid]       = e[tid]       + p[tid];
  o[tid + 256] = e[tid + 256] + p[tid + 256];
  o[tid + 512] = e[tid + 512] + p[tid + 512];
}

// ---------------- layernorm: one row per wave, vectorized -------------------
__global__ __launch_bounds__(256)
void ln_k(const float* __restrict__ x, const float* __restrict__ g,
          const float* __restrict__ bb, bf16_t* __restrict__ out) {
  const int wave = threadIdx.x >> 6, lane = threadIdx.x & 63;
  const int row = blockIdx.x * 4 + wave;
  const float* xr = x + (size_t)row * 768;
  f32x4 v[3];
#pragma unroll
  for (int c = 0; c < 3; ++c) v[c] = *(const f32x4*)&xr[c * 256 + lane * 4];
  float s = 0.0f;
#pragma unroll
  for (int c = 0; c < 3; ++c)
#pragma unroll
    for (int i = 0; i < 4; ++i) s += v[c][i];
#pragma unroll
  for (int off = 32; off; off >>= 1) s += __shfl_xor(s, off);
  const float mu = s * (1.0f / 768.0f);
  float s2 = 0.0f;
#pragma unroll
  for (int c = 0; c < 3; ++c)
#pragma unroll
    for (int i = 0; i < 4; ++i) {
      const float d = v[c][i] - mu;
      s2 += d * d;
    }
#pragma unroll
  for (int off = 32; off; off >>= 1) s2 += __shfl_xor(s2, off);
  const float rstd = rsqrtf(s2 * (1.0f / 768.0f) + 1e-5f);
  bf16_t* orow = out + (size_t)row * 768;
#pragma unroll
  for (int c = 0; c < 3; ++c) {
    const f32x4 gv = *(const f32x4*)&g[c * 256 + lane * 4];
    const f32x4 bv = *(const f32x4*)&bb[c * 256 + lane * 4];
    bf16x4 o;
#pragma unroll
    for (int i = 0; i < 4; ++i)
      o[i] = (bf16_t)((v[c][i] - mu) * rstd * gv[i] + bv[i]);
    *(bf16x4*)&orow[c * 256 + lane * 4] = o;
  }
}

// ---------------- gemm8p: 256x256, BK=32, 8 waves, 2 blocks/CU --------------
// LDS: 2 buffers x (A[256][32] + B[256][32]) bf16 = 64 KiB (+epilogue pad).
// Layout: 2 tile-rows (64B each) packed per 128B LDS row; chunk XOR-swizzle
// c' = c ^ (ldsrow&7) (same involution class as the 0-conflict BK=64 layout).
// Per K-tile: 4 glds/thread, 12 ds_read/wave, 32 MFMA/wave, 3 barriers.
// Boundary: counted vmcnt(4) (t+1's 4 glds stay in flight).
template <bool BIAS, bool RELU, bool OUTF32, int SUPER>
__global__ __launch_bounds__(512, 4)
void gemm8p(const bf16_t* __restrict__ A, const bf16_t* __restrict__ BT,
            const float* __restrict__ bias,
            float* __restrict__ outF, bf16_t* __restrict__ outB,
            int M, int N, int K) {
  extern __shared__ char smem[];  // 69632 bytes
  const int NT_TILES = K >> 5;    // BK=32
  const int tilesM = M >> 8;
  const int cpx = gridDim.x >> 3;  // grid % 8 == 0
  const int blk = ((int)blockIdx.x & 7) * cpx + ((int)blockIdx.x >> 3);
  int tm, tn;
  if (SUPER > 0) {
    const int grp = SUPER * tilesM;
    const int g = blk / grp, r = blk % grp;
    tm = r / SUPER;
    tn = g * SUPER + r % SUPER;
  } else {
    tm = blk % tilesM;
    tn = blk / tilesM;
  }
  const int tid = threadIdx.x;
  const int lane = tid & 63, wave = tid >> 6;
  const int wr = wave >> 2, wc = wave & 3;  // 2 x 4
  const int lrow = lane & 15, koct = lane >> 4;

  // ---- staging sources (pre-inverse-swizzled) ----
  // dest byte (within region) = j*8192 + tid*16: ldsrow = j*64 + (tid>>3),
  // stored chunk c = tid&7, unswizzled c0 = c ^ (ldsrow&7) = (tid&7)^((tid>>3)&7),
  // tile row R = 2*(tid>>3) + (c0>>2) (+ j*128), k-byte = (c0&3)*16.
  const size_t rowB = (size_t)K * 2;  // bytes per tile row
  const int c0 = (tid & 7) ^ ((tid >> 3) & 7);
  const int Rloc = ((tid >> 3) << 1) + (c0 >> 2);
  const int koff = (c0 & 3) << 4;
  const char* gA0 = (const char*)(A + (size_t)tm * 256 * K) + (size_t)Rloc * rowB + koff;
  const char* gB0 = (const char*)(BT + (size_t)tn * 256 * K) + (size_t)Rloc * rowB + koff;

  // ---- fragment read offsets (swizzled) ----
  // tile row R = base + lrow: ldsrow = base/2 + (lrow>>1), chunk = (lrow&1)*4+koct,
  // stored chunk = chunk ^ (ldsrow&7); base/2 multiple of 8 -> ldsrow&7 = (lrow>>1)&7.
  const int lrh = lrow >> 1;
  const int fchunk = (((lrow & 1) << 2) | koct) ^ (lrh & 7);
  const int aB0 = (wr * 64 + lrh) * 128 + (fchunk << 4);          // + mi*1024
  const int bB0 = 16384 + (wc * 32 + lrh) * 128 + (fchunk << 4);  // + ni*1024

  auto stage = [&](int t) {
    char* d = smem + ((t & 1) << 15);  // 32 KiB buffers
    const size_t kb = (size_t)t * 64;  // 64 bytes of K per tile
    GLD16(gA0 + kb,              d + tid * 16);
    GLD16(gA0 + 128 * rowB + kb, d + 8192 + tid * 16);
    GLD16(gB0 + kb,              d + 16384 + tid * 16);
    GLD16(gB0 + 128 * rowB + kb, d + 24576 + tid * 16);
  };

  stage(0); stage(1);

  f32x4 acc[8][4] = {};

  for (int t = 0; t < NT_TILES; ++t) {
    const char* rb = smem + ((t & 1) << 15);
    const bool pf = (t + 2) < NT_TILES;
    if (t == NT_TILES - 1) asm volatile("s_waitcnt vmcnt(0)" ::: "memory");
    else                   asm volatile("s_waitcnt vmcnt(4)" ::: "memory");
    barrier_raw();

    bf16x8 a[8], b[4];
    // ---- P0: read a0-7, b0-1; convoy barrier; 16 MFMA ----
#pragma unroll
    for (int mi = 0; mi < 8; ++mi) a[mi] = *(const bf16x8*)(rb + aB0 + mi * 1024);
#pragma unroll
    for (int ni = 0; ni < 2; ++ni) b[ni] = *(const bf16x8*)(rb + bB0 + ni * 1024);
    barrier_raw();
    __builtin_amdgcn_s_setprio(1);
#pragma unroll
    for (int mi = 0; mi < 8; ++mi)
#pragma unroll
      for (int ni = 0; ni < 2; ++ni)
        acc[mi][ni] = mfma16(a[mi], b[ni], acc[mi][ni]);
    __builtin_amdgcn_s_setprio(0);

    // ---- P1: read b2-3; 16 MFMA; drain; stage(t+2) ----
#pragma unroll
    for (int ni = 2; ni < 4; ++ni) b[ni] = *(const bf16x8*)(rb + bB0 + ni * 1024);
    __builtin_amdgcn_s_setprio(1);
#pragma unroll
    for (int mi = 0; mi < 8; ++mi)
#pragma unroll
      for (int ni = 2; ni < 4; ++ni)
        acc[mi][ni] = mfma16(a[mi], b[ni], acc[mi][ni]);
    __builtin_amdgcn_s_setprio(0);
    lgkm0();
    barrier_raw();
    if (pf) stage(t + 2);
  }

  // ---- epilogue: per-wave LDS restage -> vectorized stores ----
  barrier_raw();
  const int row0 = tm * 256 + wr * 128, col0 = tn * 256 + wc * 64;
  float bv[4];
#pragma unroll
  for (int ni = 0; ni < 4; ++ni)
    bv[ni] = BIAS ? bias[col0 + ni * 16 + lrow] : 0.0f;

  if (OUTF32) {
    float* lf = (float*)smem + wave * (32 * 68);  // 8*8704B = 69632 total
#pragma unroll
    for (int ph = 0; ph < 4; ++ph) {
#pragma unroll
      for (int mm = 0; mm < 2; ++mm) {
        const int mi = ph * 2 + mm;
#pragma unroll
        for (int ni = 0; ni < 4; ++ni)
#pragma unroll
          for (int r = 0; r < 4; ++r) {
            float v = acc[mi][ni][r] + bv[ni];
            if (RELU) v = fmaxf(v, 0.0f);
            lf[(mm * 16 + koct * 4 + r) * 68 + ni * 16 + lrow] = v;
          }
      }
#pragma unroll
      for (int j = 0; j < 8; ++j) {
        const int lr = j * 4 + koct;
        const int lc = lrow * 4;
        f32x4 v4 = *(const f32x4*)&lf[lr * 68 + lc];
        *(f32x4*)&outF[(size_t)(row0 + ph * 32 + lr) * N + col0 + lc] = v4;
      }
    }
  } else {
    bf16_t* lb = (bf16_t*)smem + wave * (32 * 72);
#pragma unroll
    for (int ph = 0; ph < 4; ++ph) {
#pragma unroll
      for (int mm = 0; mm < 2; ++mm) {
        const int mi = ph * 2 + mm;
#pragma unroll
        for (int ni = 0; ni < 4; ++ni)
#pragma unroll
          for (int r = 0; r < 4; ++r) {
            float v = acc[mi][ni][r] + bv[ni];
            if (RELU) v = fmaxf(v, 0.0f);
            lb[(mm * 16 + koct * 4 + r) * 72 + ni * 16 + lrow] = (bf16_t)v;
          }
      }
#pragma unroll
      for (int j = 0; j < 4; ++j) {
        const int lr = j * 8 + (lane >> 3);
        const int lc = (lane & 7) * 8;
        bf16x8 v8 = *(const bf16x8*)&lb[lr * 72 + lc];
        *(bf16x8*)&outB[(size_t)(row0 + ph * 32 + lr) * N + col0 + lc] = v8;
      }
    }
  }
}

// ---------------- gemmS: 64x128 tile, 3-slot pipeline (for N=768 GEMMs) -----
template <bool BIAS, bool RELU, bool RESID, bool OUTF32>
__global__ __launch_bounds__(256, 2)
void gemmS(const bf16_t* __restrict__ A, const bf16_t* __restrict__ BT,
           const float* __restrict__ bias, const float* __restrict__ resid,
           float* __restrict__ outF, bf16_t* __restrict__ outB,
           int M, int N, int K) {
  extern __shared__ char smem[];  // 3 * 24576 bytes
  const int NT = K >> 6;
  const int tiles_n = N >> 7;
  const int tm = blockIdx.x / tiles_n, tn = blockIdx.x % tiles_n;
  const int tid = threadIdx.x;
  const int wave = tid >> 6, lane = tid & 63;
  const int wr = wave >> 1, wc = wave & 1;
  const int lrow = lane & 15, koct = lane >> 4;

  const char* gA[2];
  const char* gB[4];
  {
    const char* Ab = (const char*)(A + (size_t)tm * 64 * K);
    const char* Bb = (const char*)(BT + (size_t)tn * 128 * K);
#pragma unroll
    for (int i = 0; i < 2; ++i) {
      const int off = i * 4096 + tid * 16;
      const int row = off >> 7;
      const int src = off ^ ((row & 7) << 4);
      gA[i] = Ab + (size_t)row * (2 * K) + (src & 127);
    }
#pragma unroll
    for (int i = 0; i < 4; ++i) {
      const int off = i * 4096 + tid * 16;
      const int row = off >> 7;
      const int src = off ^ ((row & 7) << 4);
      gB[i] = Bb + (size_t)row * (2 * K) + (src & 127);
    }
  }

  int aoff[2][2], boff[2][4];
#pragma unroll
  for (int kk = 0; kk < 2; ++kk) {
#pragma unroll
    for (int mi = 0; mi < 2; ++mi) {
      const int row = wr * 32 + mi * 16 + lrow;
      aoff[kk][mi] = (row * 128 + kk * 64 + koct * 16) ^ ((lrow & 7) << 4);
    }
#pragma unroll
    for (int ni = 0; ni < 4; ++ni) {
      const int row = wc * 64 + ni * 16 + lrow;
      boff[kk][ni] = 8192 + ((row * 128 + kk * 64 + koct * 16) ^ ((lrow & 7) << 4));
    }
  }

#pragma unroll
  for (int t = 0; t < 2; ++t) {
    char* sb = smem + t * 24576;
    const size_t kb = (size_t)t * 128;
    GLD16(gA[0] + kb, sb + tid * 16);
    GLD16(gA[1] + kb, sb + 4096 + tid * 16);
    GLD16(gB[0] + kb, sb + 8192 + tid * 16);
    GLD16(gB[1] + kb, sb + 12288 + tid * 16);
    GLD16(gB[2] + kb, sb + 16384 + tid * 16);
    GLD16(gB[3] + kb, sb + 20480 + tid * 16);
  }

  f32x4 acc[2][4] = {};

  for (int t = 0; t < NT; ++t) {
    char* sb = smem + (t % 3) * 24576;
    char* sb2 = smem + ((t + 2) % 3) * 24576;
    const bool pf = (t + 2) < NT;
    const size_t kb2 = (size_t)(t + 2) * 128;

    if (t == NT - 1) asm volatile("s_waitcnt vmcnt(0)" ::: "memory");
    else             asm volatile("s_waitcnt vmcnt(6)" ::: "memory");
    barrier_raw();

#pragma unroll
    for (int kk = 0; kk < 2; ++kk) {
      bf16x8 af[2], bfr[4];
#pragma unroll
      for (int mi = 0; mi < 2; ++mi)
        af[mi] = *(const bf16x8*)(sb + aoff[kk][mi]);
#pragma unroll
      for (int ni = 0; ni < 4; ++ni)
        bfr[ni] = *(const bf16x8*)(sb + boff[kk][ni]);
      if (pf) {
        if (kk == 0) {
          GLD16(gA[0] + kb2, sb2 + tid * 16);
          GLD16(gA[1] + kb2, sb2 + 4096 + tid * 16);
          GLD16(gB[0] + kb2, sb2 + 8192 + tid * 16);
        } else {
          GLD16(gB[1] + kb2, sb2 + 12288 + tid * 16);
          GLD16(gB[2] + kb2, sb2 + 16384 + tid * 16);
          GLD16(gB[3] + kb2, sb2 + 20480 + tid * 16);
        }
      }
      barrier_raw();
      __builtin_amdgcn_s_setprio(1);
#pragma unroll
      for (int mi = 0; mi < 2; ++mi)
#pragma unroll
        for (int ni = 0; ni < 4; ++ni)
          acc[mi][ni] = mfma16(af[mi], bfr[ni], acc[mi][ni]);
      __builtin_amdgcn_s_setprio(0);
    }
  }

  const int row0 = tm * 64 + wr * 32, col0 = tn * 128 + wc * 64;
#pragma unroll
  for (int ni = 0; ni < 4; ++ni) {
    const int col = col0 + ni * 16 + lrow;
    const float bv = BIAS ? bias[col] : 0.0f;
#pragma unroll
    for (int mi = 0; mi < 2; ++mi) {
#pragma unroll
      for (int r = 0; r < 4; ++r) {
        const int row = row0 + mi * 16 + koct * 4 + r;
        float v = acc[mi][ni][r] + bv;
        if (RELU) v = fmaxf(v, 0.0f);
        const size_t idx = (size_t)row * N + col;
        if (RESID) v += resid[idx];
        if (OUTF32) outF[idx] = v;
        else        outB[idx] = (bf16_t)v;
      }
    }
  }
}

// ---------------- fused causal attention (flash-style, swizzled LDS) --------
__global__ __launch_bounds__(256)
void attn_k(const bf16_t* __restrict__ qkv, bf16_t* __restrict__ ab) {
  __shared__ __align__(16) bf16_t Qs[64 * 64];
  __shared__ __align__(16) bf16_t Ks[64 * 64];
  __shared__ __align__(16) bf16_t Vt[64 * 64];
  __shared__ __align__(16) bf16_t Ps[4][16 * 64];
  const int qt = blockIdx.x, h = blockIdx.y, b = blockIdx.z;
  const int tid = threadIdx.x;
  const int wave = tid >> 6, lane = tid & 63;
  const int lrow = lane & 15, koct = lane >> 4;
  const float scale = 0.03608439182435161f;  // 1/sqrt(768)

  const size_t RS = 2304;
  const bf16_t* qbase = qkv + h * 64;
  const bf16_t* kbase = qkv + 768 + h * 64;
  const bf16_t* vbase = qkv + 1536 + h * 64;

  const int sr = tid >> 3;
  const int sc = (((tid & 7) ^ (sr & 7)) << 3);

  {
#pragma unroll
    for (int i = 0; i < 2; ++i)
      GLD16(qbase + (size_t)(b * 1024 + qt * 64 + i * 32 + sr) * RS + sc,
            Qs + i * 2048 + tid * 8);
  }
  __syncthreads();
  bf16x8 qf[2];
  qf[0] = *(const bf16x8*)&Qs[SW64(wave * 16 + lrow, koct * 8)];
  qf[1] = *(const bf16x8*)&Qs[SW64(wave * 16 + lrow, 32 + koct * 8)];

  float m_r[4], l_r[4];
  f32x4 o[4] = {};
#pragma unroll
  for (int r = 0; r < 4; ++r) { m_r[r] = -1e30f; l_r[r] = 0.0f; }

  for (int kt = 0; kt <= qt; ++kt) {
    __syncthreads();
    {
#pragma unroll
      for (int i = 0; i < 2; ++i)
        GLD16(kbase + (size_t)(b * 1024 + kt * 64 + i * 32 + sr) * RS + sc,
              Ks + i * 2048 + tid * 8);
    }
    {
      const int kvr = lane;
      const int d0 = wave * 16;
      const bf16_t* vr = vbase + (size_t)(b * 1024 + kt * 64 + kvr) * RS + d0;
      bf16x8 v0 = *(const bf16x8*)vr;
      bf16x8 v1 = *(const bf16x8*)(vr + 8);
#pragma unroll
      for (int j = 0; j < 8; ++j) {
        Vt[(d0 + j) * 64 + (kvr ^ (j << 3))]     = v0[j];
        Vt[(d0 + 8 + j) * 64 + (kvr ^ (j << 3))] = v1[j];
      }
    }
    __syncthreads();

    f32x4 s[4] = {};
#pragma unroll
    for (int ni = 0; ni < 4; ++ni) {
      bf16x8 kf0 = *(const bf16x8*)&Ks[SW64(ni * 16 + lrow, koct * 8)];
      bf16x8 kf1 = *(const bf16x8*)&Ks[SW64(ni * 16 + lrow, 32 + koct * 8)];
      s[ni] = mfma16(qf[0], kf0, s[ni]);
      s[ni] = mfma16(qf[1], kf1, s[ni]);
    }

    const int qrow = qt * 64 + wave * 16 + koct * 4;
    float rm[4];
#pragma unroll
    for (int r = 0; r < 4; ++r) rm[r] = -1e30f;
#pragma unroll
    for (int ni = 0; ni < 4; ++ni) {
      const int kcol = kt * 64 + ni * 16 + lrow;
#pragma unroll
      for (int r = 0; r < 4; ++r) {
        float v = s[ni][r] * scale;
        if (kcol > qrow + r) v = -1e30f;
        s[ni][r] = v;
        rm[r] = fmaxf(rm[r], v);
      }
    }
#pragma unroll
    for (int r = 0; r < 4; ++r) RED16_MAX(rm[r]);
    float corr[4], ps[4];
#pragma unroll
    for (int r = 0; r < 4; ++r) {
      const float mn = fmaxf(m_r[r], rm[r]);
      corr[r] = __expf(m_r[r] - mn);
      m_r[r] = mn;
      ps[r] = 0.0f;
    }
#pragma unroll
    for (int ni = 0; ni < 4; ++ni)
#pragma unroll
      for (int r = 0; r < 4; ++r) {
        const float p = __expf(s[ni][r] - m_r[r]);
        s[ni][r] = p;
        ps[r] += p;
      }
#pragma unroll
    for (int r = 0; r < 4; ++r) RED16_SUM(ps[r]);
#pragma unroll
    for (int r = 0; r < 4; ++r) l_r[r] = l_r[r] * corr[r] + ps[r];
#pragma unroll
    for (int ni = 0; ni < 4; ++ni)
#pragma unroll
      for (int r = 0; r < 4; ++r) o[ni][r] *= corr[r];

#pragma unroll
    for (int ni = 0; ni < 4; ++ni)
#pragma unroll
      for (int r = 0; r < 4; ++r) {
        const int prow = koct * 4 + r;
        Ps[wave][prow * 64 + ((ni * 16 + lrow) ^ ((prow & 7) << 3))] =
            (bf16_t)s[ni][r];
      }
    __syncthreads();

    bf16x8 pa0 = *(const bf16x8*)&Ps[wave][SW64(lrow, koct * 8)];
    bf16x8 pa1 = *(const bf16x8*)&Ps[wave][SW64(lrow, 32 + koct * 8)];
#pragma unroll
    for (int ni = 0; ni < 4; ++ni) {
      bf16x8 vf0 = *(const bf16x8*)&Vt[SW64(ni * 16 + lrow, koct * 8)];
      bf16x8 vf1 = *(const bf16x8*)&Vt[SW64(ni * 16 + lrow, 32 + koct * 8)];
      o[ni] = mfma16(pa0, vf0, o[ni]);
      o[ni] = mfma16(pa1, vf1, o[ni]);
    }
  }

#pragma unroll
  for (int r = 0; r < 4; ++r) {
    const float inv = 1.0f / l_r[r];
    const int row = qt * 64 + wave * 16 + koct * 4 + r;
#pragma unroll
    for (int ni = 0; ni < 4; ++ni)
      ab[(size_t)(b * 1024 + row) * 768 + h * 64 + ni * 16 + lrow] =
          (bf16_t)(o[ni][r] * inv);
  }
}

// ---------------------------------------------------------------------------
extern "C" void kernel_launch(void* const* d_in, const int* in_sizes, int n_in,
                              void* d_out, int out_size, void* d_ws, size_t ws_size,
                              hipStream_t stream) {
  (void)in_sizes; (void)n_in; (void)out_size; (void)ws_size;
  const int*   tok   = (const int*)d_in[0];
  const float* emb   = (const float*)d_in[1];
  const float* pe    = (const float*)d_in[2];
  const float* ln1_g = (const float*)d_in[3];
  const float* ln1_b = (const float*)d_in[4];
  const float* wq    = (const float*)d_in[5];
  const float* bq    = (const float*)d_in[6];
  const float* wk    = (const float*)d_in[7];
  const float* bk    = (const float*)d_in[8];
  const float* wv    = (const float*)d_in[9];
  const float* bv    = (const float*)d_in[10];
  const float* wo    = (const float*)d_in[11];
  const float* bo    = (const float*)d_in[12];
  const float* ln2_g = (const float*)d_in[13];
  const float* ln2_b = (const float*)d_in[14];
  const float* w1    = (const float*)d_in[15];
  const float* b1    = (const float*)d_in[16];
  const float* w2    = (const float*)d_in[17];
  const float* b2    = (const float*)d_in[18];
  const float* lnf_g = (const float*)d_in[19];
  const float* lnf_b = (const float*)d_in[20];
  const float* w_out = (const float*)d_in[21];
  float* out = (float*)d_out;

  char* ws = (char*)d_ws;
  size_t off = 0;
  auto alloc = [&](size_t bytes) -> void* {
    void* p = ws + off;
    off += (bytes + 255) & ~(size_t)255;
    return p;
  };
  float*  xf      = (float*)alloc(4096ull * 768 * 4);
  bf16_t* hb      = (bf16_t*)alloc(4096ull * 768 * 2);
  bf16_t* qkvb    = (bf16_t*)alloc(4096ull * 2304 * 2);
  bf16_t* ab      = (bf16_t*)alloc(4096ull * 768 * 2);
  bf16_t* fb      = (bf16_t*)alloc(4096ull * 3072 * 2);
  float*  qkvbias = (float*)alloc(4ull * 2304 * 4);
  bf16_t* wqkvT   = (bf16_t*)alloc(4ull * 2304 * 768 * 2);
  bf16_t* woT     = (bf16_t*)alloc(4ull * 768 * 768 * 2);
  bf16_t* w1T     = (bf16_t*)alloc(4ull * 3072 * 768 * 2);
  bf16_t* w2T     = (bf16_t*)alloc(4ull * 768 * 3072 * 2);
  bf16_t* woutT   = (bf16_t*)alloc(32000ull * 768 * 2);

  // ---- weight convert+transpose (batched over layers via gridDim.z) ----
  tconv_k<<<dim3(24, 24, 4), 256, 0, stream>>>(wq, wqkvT, 768, 768,
      768ull * 768, 2304ull * 768);
  tconv_k<<<dim3(24, 24, 4), 256, 0, stream>>>(wk, wqkvT + 768ull * 768, 768, 768,
      768ull * 768, 2304ull * 768);
  tconv_k<<<dim3(24, 24, 4), 256, 0, stream>>>(wv, wqkvT + 2ull * 768 * 768, 768, 768,
      768ull * 768, 2304ull * 768);
  tconv_k<<<dim3(24, 24, 4), 256, 0, stream>>>(wo, woT, 768, 768,
      768ull * 768, 768ull * 768);
  tconv_k<<<dim3(96, 24, 4), 256, 0, stream>>>(w1, w1T, 768, 3072,
      768ull * 3072, 3072ull * 768);
  tconv_k<<<dim3(24, 96, 4), 256, 0, stream>>>(w2, w2T, 3072, 768,
      3072ull * 768, 768ull * 3072);
  tconv_k<<<dim3(1000, 24, 1), 256, 0, stream>>>(w_out, woutT, 768, 32000, 0, 0);
  qkvbias_k<<<4, 256, 0, stream>>>(bq, bk, bv, qkvbias);

  // ---- forward ----
  embed_k<<<4096, 256, 0, stream>>>(tok, emb, pe, xf);

  const size_t SMEM8P = 69632;       // 68 KiB (gemm8p BK=32, 2 blocks/CU)
  const size_t SMEMS  = 3 * 24576;   // 72 KiB (gemmS)
  for (int l = 0; l < 4; ++l) {
    ln_k<<<1024, 256, 0, stream>>>(xf, ln1_g + l * 768, ln1_b + l * 768, hb);
    gemm8p<true, false, false, 0><<<16 * 9, 512, SMEM8P, stream>>>(
        hb, wqkvT + (size_t)l * 2304 * 768, qkvbias + l * 2304,
        nullptr, qkvb, 4096, 2304, 768);
    attn_k<<<dim3(16, 12, 4), 256, 0, stream>>>(qkvb, ab);
    gemmS<true, false, true, true><<<64 * 6, 256, SMEMS, stream>>>(
        ab, woT + (size_t)l * 768 * 768, bo + l * 768,
        xf, xf, nullptr, 4096, 768, 768);
    ln_k<<<1024, 256, 0, stream>>>(xf, ln2_g + l * 768, ln2_b + l * 768, hb);
    gemm8p<true, true, false, 0><<<16 * 12, 512, SMEM8P, stream>>>(
        hb, w1T + (size_t)l * 3072 * 768, b1 + l * 3072,
        nullptr, fb, 4096, 3072, 768);
    gemmS<true, false, true, true><<<64 * 6, 256, SMEMS, stream>>>(
        fb, w2T + (size_t)l * 768 * 3072, b2 + l * 768,
        xf, xf, nullptr, 4096, 768, 3072);
  }
  ln_k<<<1024, 256, 0, stream>>>(xf, lnf_g, lnf_b, hb);
  gemm8p<false, false, true, 5><<<16 * 125, 512, SMEM8P, stream>>>(
      hb, woutT, nullptr, out, nullptr, 4096, 32000, 768);
}

// Round 14
// 984.216 us; speedup vs baseline: 4.1969x; 4.1969x over previous
//
#include <hip/hip_runtime.h>

// ---------------------------------------------------------------------------
// miniGPT forward: 4 layers, D=768, H=12, HID=3072, V=32000, B=4, S=1024
// Round 14: exact revert to the round-7 champion (985 us): gemm8p 256x256
// BK=64 (512,2), supertile SUPER=5 + NT stores on vocab, LDS-staged epilogue;
// gemmS for WO/FFN2; attn QBLK=64 swizzled; ln_k block-per-row.
// ---------------------------------------------------------------------------

typedef __bf16 bf16_t;
typedef bf16_t bf16x8 __attribute__((ext_vector_type(8)));
typedef float f32x4 __attribute__((ext_vector_type(4)));

#define GLD16(G, L) __builtin_amdgcn_global_load_lds(                          \
    (const __attribute__((address_space(1))) unsigned int*)(const void*)(G),   \
    (__attribute__((address_space(3))) unsigned int*)(void*)(L), 16, 0, 0)

__device__ __forceinline__ f32x4 mfma16(bf16x8 a, bf16x8 b, f32x4 c) {
  return __builtin_amdgcn_mfma_f32_16x16x32_bf16(a, b, c, 0, 0, 0);
}

__device__ __forceinline__ void barrier_raw() {
  asm volatile("s_barrier" ::: "memory");
}

#define RED16_MAX(x) { x = fmaxf(x, __shfl_xor(x, 1)); x = fmaxf(x, __shfl_xor(x, 2)); \
                       x = fmaxf(x, __shfl_xor(x, 4)); x = fmaxf(x, __shfl_xor(x, 8)); }
#define RED16_SUM(x) { x += __shfl_xor(x, 1); x += __shfl_xor(x, 2); \
                       x += __shfl_xor(x, 4); x += __shfl_xor(x, 8); }

__device__ __forceinline__ int SW64(int row, int col) {
  return row * 64 + (col ^ ((row & 7) << 3));
}

// ---------------- transpose + f32->bf16 convert: in[K][N] -> out[N][K] ------
__global__ __launch_bounds__(256)
void tconv_k(const float* __restrict__ in, bf16_t* __restrict__ out, int K, int N,
             size_t in_ls, size_t out_ls) {
  __shared__ float tile[32][33];
  in  += (size_t)blockIdx.z * in_ls;
  out += (size_t)blockIdx.z * out_ls;
  const int n0 = blockIdx.x * 32, k0 = blockIdx.y * 32;
  const int tx = threadIdx.x & 31, ty = threadIdx.x >> 5;
#pragma unroll
  for (int j = 0; j < 4; ++j)
    tile[ty + j * 8][tx] = in[(size_t)(k0 + ty + j * 8) * N + n0 + tx];
  __syncthreads();
#pragma unroll
  for (int j = 0; j < 4; ++j)
    out[(size_t)(n0 + ty + j * 8) * K + k0 + tx] = (bf16_t)tile[tx][ty + j * 8];
}

// ---------------- concat q/k/v biases per layer -> [L][2304] ----------------
__global__ void qkvbias_k(const float* __restrict__ bq, const float* __restrict__ bk,
                          const float* __restrict__ bv, float* __restrict__ out) {
  const int l = blockIdx.x;
  for (int j = threadIdx.x; j < 2304; j += 256) {
    float v = (j < 768) ? bq[l * 768 + j]
            : (j < 1536) ? bk[l * 768 + j - 768]
                         : bv[l * 768 + j - 1536];
    out[l * 2304 + j] = v;
  }
}

// ---------------- embedding + positional encoding ---------------------------
__global__ __launch_bounds__(256)
void embed_k(const int* __restrict__ tok, const float* __restrict__ emb,
             const float* __restrict__ pe, float* __restrict__ xf) {
  const int row = blockIdx.x, tid = threadIdx.x;
  const int s = row & 1023;
  const int t = tok[row];
  float* o = xf + (size_t)row * 768;
  const float* e = emb + (size_t)t * 768;
  const float* p = pe + (size_t)s * 768;
  o[tid]       = e[tid]       + p[tid];
  o[tid + 256] = e[tid + 256] + p[tid + 256];
  o[tid + 512] = e[tid + 512] + p[tid + 512];
}

// ---------------- layernorm (fp32 in, bf16 out), one block per row ----------
__global__ __launch_bounds__(256)
void ln_k(const float* __restrict__ x, const float* __restrict__ g,
          const float* __restrict__ bb, bf16_t* __restrict__ out) {
  const int row = blockIdx.x, tid = threadIdx.x;
  const int wave = tid >> 6, lane = tid & 63;
  const float* xr = x + (size_t)row * 768;
  float v0 = xr[tid], v1 = xr[tid + 256], v2 = xr[tid + 512];
  float s = v0 + v1 + v2;
  __shared__ float red[4];
#pragma unroll
  for (int off = 32; off; off >>= 1) s += __shfl_xor(s, off);
  if (lane == 0) red[wave] = s;
  __syncthreads();
  const float mu = (red[0] + red[1] + red[2] + red[3]) * (1.0f / 768.0f);
  const float d0 = v0 - mu, d1 = v1 - mu, d2 = v2 - mu;
  float s2 = d0 * d0 + d1 * d1 + d2 * d2;
#pragma unroll
  for (int off = 32; off; off >>= 1) s2 += __shfl_xor(s2, off);
  __syncthreads();
  if (lane == 0) red[wave] = s2;
  __syncthreads();
  const float rstd = rsqrtf((red[0] + red[1] + red[2] + red[3]) * (1.0f / 768.0f) + 1e-5f);
  bf16_t* orow = out + (size_t)row * 768;
  orow[tid]       = (bf16_t)(d0 * rstd * g[tid]       + bb[tid]);
  orow[tid + 256] = (bf16_t)(d1 * rstd * g[tid + 256] + bb[tid + 256]);
  orow[tid + 512] = (bf16_t)(d2 * rstd * g[tid + 512] + bb[tid + 512]);
}

// ---------------- gemm8p: 256x256, BK=64, 8 waves, convoyed 4-phase ---------
// LDS: 2 x (A[256][64] + B[256][64]) = 128 KiB, XOR-swizzled. Epilogue: LDS
// re-staged vectorized stores. SUPER>0: blocks grouped as tilesM x SUPER
// supertiles (tn-fast inside) for L2-resident concurrent working set.
template <bool BIAS, bool RELU, bool OUTF32, bool NT, int SUPER>
__global__ __launch_bounds__(512, 2)
void gemm8p(const bf16_t* __restrict__ A, const bf16_t* __restrict__ BT,
            const float* __restrict__ bias,
            float* __restrict__ outF, bf16_t* __restrict__ outB,
            int M, int N, int K) {
  extern __shared__ char smem[];  // 131072 bytes
  const int NT_TILES = K >> 6;
  const int tilesM = M >> 8;
  const int cpx = gridDim.x >> 3;  // grid % 8 == 0
  const int blk = ((int)blockIdx.x & 7) * cpx + ((int)blockIdx.x >> 3);
  int tm, tn;
  if (SUPER > 0) {
    const int grp = SUPER * tilesM;
    const int g = blk / grp, r = blk % grp;
    tm = r / SUPER;
    tn = g * SUPER + r % SUPER;
  } else {
    tm = blk % tilesM;
    tn = blk / tilesM;
  }
  const int tid = threadIdx.x;
  const int lane = tid & 63, wave = tid >> 6;
  const int wr = wave >> 2, wc = wave & 3;  // 2 x 4
  const int lrow = lane & 15, koct = lane >> 4;

  const size_t rowK = (size_t)K * 2;
  const int srow = tid >> 3;
  const int cswz = ((tid & 7) ^ (srow & 7)) << 4;
  const char* gA = (const char*)(A + (size_t)tm * 256 * K) + (size_t)srow * rowK + cswz;
  const char* gB = (const char*)(BT + (size_t)tn * 256 * K) + (size_t)srow * rowK + cswz;

  const int swz = (lrow & 7) << 4;
  const int aB0 = (wr * 128 + lrow) * 128 + ((koct * 16) ^ swz);
  const int bB0 = 32768 + (wc * 64 + lrow) * 128 + ((koct * 16) ^ swz);

  auto stageA = [&](int t) {
    char* d = smem + ((t & 1) << 16);
    const size_t kb = (size_t)t * 128;
    GLD16(gA + kb,              d + tid * 16);
    GLD16(gA + 64 * rowK + kb,  d + 8192 + tid * 16);
    GLD16(gA + 128 * rowK + kb, d + 16384 + tid * 16);
    GLD16(gA + 192 * rowK + kb, d + 24576 + tid * 16);
  };
  auto stageB = [&](int t) {
    char* d = smem + ((t & 1) << 16) + 32768;
    const size_t kb = (size_t)t * 128;
    GLD16(gB + kb,              d + tid * 16);
    GLD16(gB + 64 * rowK + kb,  d + 8192 + tid * 16);
    GLD16(gB + 128 * rowK + kb, d + 16384 + tid * 16);
    GLD16(gB + 192 * rowK + kb, d + 24576 + tid * 16);
  };

  stageA(0); stageB(0);
  stageA(1); stageB(1);

  f32x4 acc[8][4] = {};

  for (int t = 0; t < NT_TILES; ++t) {
    const char* rb = smem + ((t & 1) << 16);
    const bool pf = (t + 2) < NT_TILES;
    if (t == NT_TILES - 1) asm volatile("s_waitcnt vmcnt(0)" ::: "memory");
    else                   asm volatile("s_waitcnt vmcnt(8)" ::: "memory");
    barrier_raw();

    bf16x8 a0[4][2], a1[4][2], b[4][2];
    // ---- P0: read a0-3, b0-1; convoy barrier; mfma q0 ----
#pragma unroll
    for (int mi = 0; mi < 4; ++mi) {
      const int o = aB0 + mi * 2048;
      a0[mi][0] = *(const bf16x8*)(rb + o);
      a0[mi][1] = *(const bf16x8*)(rb + (o ^ 64));
    }
#pragma unroll
    for (int ni = 0; ni < 2; ++ni) {
      const int o = bB0 + ni * 2048;
      b[ni][0] = *(const bf16x8*)(rb + o);
      b[ni][1] = *(const bf16x8*)(rb + (o ^ 64));
    }
    barrier_raw();
    __builtin_amdgcn_s_setprio(1);
#pragma unroll
    for (int mi = 0; mi < 4; ++mi)
#pragma unroll
      for (int ni = 0; ni < 2; ++ni) {
        acc[mi][ni] = mfma16(a0[mi][0], b[ni][0], acc[mi][ni]);
        acc[mi][ni] = mfma16(a0[mi][1], b[ni][1], acc[mi][ni]);
      }
    __builtin_amdgcn_s_setprio(0);
    barrier_raw();

    // ---- P1: read b2-3; mfma q1; drain B region ----
#pragma unroll
    for (int ni = 2; ni < 4; ++ni) {
      const int o = bB0 + ni * 2048;
      b[ni][0] = *(const bf16x8*)(rb + o);
      b[ni][1] = *(const bf16x8*)(rb + (o ^ 64));
    }
    __builtin_amdgcn_s_setprio(1);
#pragma unroll
    for (int mi = 0; mi < 4; ++mi)
#pragma unroll
      for (int ni = 2; ni < 4; ++ni) {
        acc[mi][ni] = mfma16(a0[mi][0], b[ni][0], acc[mi][ni]);
        acc[mi][ni] = mfma16(a0[mi][1], b[ni][1], acc[mi][ni]);
      }
    __builtin_amdgcn_s_setprio(0);
    asm volatile("s_waitcnt lgkmcnt(0)" ::: "memory");
    barrier_raw();

    // ---- P2: stage B(t+2); read a4-7; mfma q2; drain A region ----
    if (pf) stageB(t + 2);
#pragma unroll
    for (int mi = 0; mi < 4; ++mi) {
      const int o = aB0 + (mi + 4) * 2048;
      a1[mi][0] = *(const bf16x8*)(rb + o);
      a1[mi][1] = *(const bf16x8*)(rb + (o ^ 64));
    }
    __builtin_amdgcn_s_setprio(1);
#pragma unroll
    for (int mi = 0; mi < 4; ++mi)
#pragma unroll
      for (int ni = 0; ni < 2; ++ni) {
        acc[mi + 4][ni] = mfma16(a1[mi][0], b[ni][0], acc[mi + 4][ni]);
        acc[mi + 4][ni] = mfma16(a1[mi][1], b[ni][1], acc[mi + 4][ni]);
      }
    __builtin_amdgcn_s_setprio(0);
    asm volatile("s_waitcnt lgkmcnt(0)" ::: "memory");
    barrier_raw();

    // ---- P3: stage A(t+2); mfma q3 ----
    if (pf) stageA(t + 2);
    __builtin_amdgcn_s_setprio(1);
#pragma unroll
    for (int mi = 0; mi < 4; ++mi)
#pragma unroll
      for (int ni = 2; ni < 4; ++ni) {
        acc[mi + 4][ni] = mfma16(a1[mi][0], b[ni][0], acc[mi + 4][ni]);
        acc[mi + 4][ni] = mfma16(a1[mi][1], b[ni][1], acc[mi + 4][ni]);
      }
    __builtin_amdgcn_s_setprio(0);
  }

  // ---- epilogue: per-wave LDS restage -> vectorized stores ----
  barrier_raw();
  const int row0 = tm * 256 + wr * 128, col0 = tn * 256 + wc * 64;
  float bv[4];
#pragma unroll
  for (int ni = 0; ni < 4; ++ni)
    bv[ni] = BIAS ? bias[col0 + ni * 16 + lrow] : 0.0f;

  if (OUTF32) {
    float* lf = (float*)smem + wave * (32 * 68);
#pragma unroll
    for (int ph = 0; ph < 4; ++ph) {
#pragma unroll
      for (int mm = 0; mm < 2; ++mm) {
        const int mi = ph * 2 + mm;
#pragma unroll
        for (int ni = 0; ni < 4; ++ni)
#pragma unroll
          for (int r = 0; r < 4; ++r) {
            float v = acc[mi][ni][r] + bv[ni];
            if (RELU) v = fmaxf(v, 0.0f);
            lf[(mm * 16 + koct * 4 + r) * 68 + ni * 16 + lrow] = v;
          }
      }
#pragma unroll
      for (int j = 0; j < 8; ++j) {
        const int lr = j * 4 + koct;   // 0..31
        const int lc = lrow * 4;       // 0..60
        f32x4 v4 = *(const f32x4*)&lf[lr * 68 + lc];
        f32x4* dst = (f32x4*)&outF[(size_t)(row0 + ph * 32 + lr) * N + col0 + lc];
        if (NT) __builtin_nontemporal_store(v4, dst);
        else    *dst = v4;
      }
    }
  } else {
    bf16_t* lb = (bf16_t*)smem + wave * (32 * 72);
#pragma unroll
    for (int ph = 0; ph < 4; ++ph) {
#pragma unroll
      for (int mm = 0; mm < 2; ++mm) {
        const int mi = ph * 2 + mm;
#pragma unroll
        for (int ni = 0; ni < 4; ++ni)
#pragma unroll
          for (int r = 0; r < 4; ++r) {
            float v = acc[mi][ni][r] + bv[ni];
            if (RELU) v = fmaxf(v, 0.0f);
            lb[(mm * 16 + koct * 4 + r) * 72 + ni * 16 + lrow] = (bf16_t)v;
          }
      }
#pragma unroll
      for (int j = 0; j < 4; ++j) {
        const int lr = j * 8 + (lane >> 3);  // 0..31
        const int lc = (lane & 7) * 8;       // 0..56
        bf16x8 v8 = *(const bf16x8*)&lb[lr * 72 + lc];
        *(bf16x8*)&outB[(size_t)(row0 + ph * 32 + lr) * N + col0 + lc] = v8;
      }
    }
  }
}

// ---------------- gemmS: 64x128 tile, 3-slot pipeline (for N=768 GEMMs) -----
template <bool BIAS, bool RELU, bool RESID, bool OUTF32>
__global__ __launch_bounds__(256, 2)
void gemmS(const bf16_t* __restrict__ A, const bf16_t* __restrict__ BT,
           const float* __restrict__ bias, const float* __restrict__ resid,
           float* __restrict__ outF, bf16_t* __restrict__ outB,
           int M, int N, int K) {
  extern __shared__ char smem[];  // 3 * 24576 bytes
  const int NT = K >> 6;
  const int tiles_n = N >> 7;
  const int tm = blockIdx.x / tiles_n, tn = blockIdx.x % tiles_n;
  const int tid = threadIdx.x;
  const int wave = tid >> 6, lane = tid & 63;
  const int wr = wave >> 1, wc = wave & 1;  // 2x2, wave = 32x64
  const int lrow = lane & 15, koct = lane >> 4;

  const char* gA[2];
  const char* gB[4];
  {
    const char* Ab = (const char*)(A + (size_t)tm * 64 * K);
    const char* Bb = (const char*)(BT + (size_t)tn * 128 * K);
#pragma unroll
    for (int i = 0; i < 2; ++i) {
      const int off = i * 4096 + tid * 16;
      const int row = off >> 7;
      const int src = off ^ ((row & 7) << 4);
      gA[i] = Ab + (size_t)row * (2 * K) + (src & 127);
    }
#pragma unroll
    for (int i = 0; i < 4; ++i) {
      const int off = i * 4096 + tid * 16;
      const int row = off >> 7;
      const int src = off ^ ((row & 7) << 4);
      gB[i] = Bb + (size_t)row * (2 * K) + (src & 127);
    }
  }

  int aoff[2][2], boff[2][4];
#pragma unroll
  for (int kk = 0; kk < 2; ++kk) {
#pragma unroll
    for (int mi = 0; mi < 2; ++mi) {
      const int row = wr * 32 + mi * 16 + lrow;
      aoff[kk][mi] = (row * 128 + kk * 64 + koct * 16) ^ ((lrow & 7) << 4);
    }
#pragma unroll
    for (int ni = 0; ni < 4; ++ni) {
      const int row = wc * 64 + ni * 16 + lrow;
      boff[kk][ni] = 8192 + ((row * 128 + kk * 64 + koct * 16) ^ ((lrow & 7) << 4));
    }
  }

#pragma unroll
  for (int t = 0; t < 2; ++t) {
    char* sb = smem + t * 24576;
    const size_t kb = (size_t)t * 128;
    GLD16(gA[0] + kb, sb + tid * 16);
    GLD16(gA[1] + kb, sb + 4096 + tid * 16);
    GLD16(gB[0] + kb, sb + 8192 + tid * 16);
    GLD16(gB[1] + kb, sb + 12288 + tid * 16);
    GLD16(gB[2] + kb, sb + 16384 + tid * 16);
    GLD16(gB[3] + kb, sb + 20480 + tid * 16);
  }

  f32x4 acc[2][4] = {};

  for (int t = 0; t < NT; ++t) {
    char* sb = smem + (t % 3) * 24576;
    char* sb2 = smem + ((t + 2) % 3) * 24576;
    const bool pf = (t + 2) < NT;
    const size_t kb2 = (size_t)(t + 2) * 128;

    if (t == NT - 1) asm volatile("s_waitcnt vmcnt(0)" ::: "memory");
    else             asm volatile("s_waitcnt vmcnt(6)" ::: "memory");
    barrier_raw();

#pragma unroll
    for (int kk = 0; kk < 2; ++kk) {
      bf16x8 af[2], bfr[4];
#pragma unroll
      for (int mi = 0; mi < 2; ++mi)
        af[mi] = *(const bf16x8*)(sb + aoff[kk][mi]);
#pragma unroll
      for (int ni = 0; ni < 4; ++ni)
        bfr[ni] = *(const bf16x8*)(sb + boff[kk][ni]);
      if (pf) {
        if (kk == 0) {
          GLD16(gA[0] + kb2, sb2 + tid * 16);
          GLD16(gA[1] + kb2, sb2 + 4096 + tid * 16);
          GLD16(gB[0] + kb2, sb2 + 8192 + tid * 16);
        } else {
          GLD16(gB[1] + kb2, sb2 + 12288 + tid * 16);
          GLD16(gB[2] + kb2, sb2 + 16384 + tid * 16);
          GLD16(gB[3] + kb2, sb2 + 20480 + tid * 16);
        }
      }
      barrier_raw();
      __builtin_amdgcn_s_setprio(1);
#pragma unroll
      for (int mi = 0; mi < 2; ++mi)
#pragma unroll
        for (int ni = 0; ni < 4; ++ni)
          acc[mi][ni] = mfma16(af[mi], bfr[ni], acc[mi][ni]);
      __builtin_amdgcn_s_setprio(0);
    }
  }

  const int row0 = tm * 64 + wr * 32, col0 = tn * 128 + wc * 64;
#pragma unroll
  for (int ni = 0; ni < 4; ++ni) {
    const int col = col0 + ni * 16 + lrow;
    const float bv = BIAS ? bias[col] : 0.0f;
#pragma unroll
    for (int mi = 0; mi < 2; ++mi) {
#pragma unroll
      for (int r = 0; r < 4; ++r) {
        const int row = row0 + mi * 16 + koct * 4 + r;
        float v = acc[mi][ni][r] + bv;
        if (RELU) v = fmaxf(v, 0.0f);
        const size_t idx = (size_t)row * N + col;
        if (RESID) v += resid[idx];
        if (OUTF32) outF[idx] = v;
        else        outB[idx] = (bf16_t)v;
      }
    }
  }
}

// ---------------- fused causal attention (flash-style, swizzled LDS) --------
__global__ __launch_bounds__(256)
void attn_k(const bf16_t* __restrict__ qkv, bf16_t* __restrict__ ab) {
  __shared__ __align__(16) bf16_t Qs[64 * 64];
  __shared__ __align__(16) bf16_t Ks[64 * 64];
  __shared__ __align__(16) bf16_t Vt[64 * 64];
  __shared__ __align__(16) bf16_t Ps[4][16 * 64];
  const int qt = blockIdx.x, h = blockIdx.y, b = blockIdx.z;
  const int tid = threadIdx.x;
  const int wave = tid >> 6, lane = tid & 63;
  const int lrow = lane & 15, koct = lane >> 4;
  const float scale = 0.03608439182435161f;  // 1/sqrt(768)

  const size_t RS = 2304;
  const bf16_t* qbase = qkv + h * 64;
  const bf16_t* kbase = qkv + 768 + h * 64;
  const bf16_t* vbase = qkv + 1536 + h * 64;

  const int sr = tid >> 3;
  const int sc = (((tid & 7) ^ (sr & 7)) << 3);

  {
#pragma unroll
    for (int i = 0; i < 2; ++i)
      GLD16(qbase + (size_t)(b * 1024 + qt * 64 + i * 32 + sr) * RS + sc,
            Qs + i * 2048 + tid * 8);
  }
  __syncthreads();
  bf16x8 qf[2];
  qf[0] = *(const bf16x8*)&Qs[SW64(wave * 16 + lrow, koct * 8)];
  qf[1] = *(const bf16x8*)&Qs[SW64(wave * 16 + lrow, 32 + koct * 8)];

  float m_r[4], l_r[4];
  f32x4 o[4] = {};
#pragma unroll
  for (int r = 0; r < 4; ++r) { m_r[r] = -1e30f; l_r[r] = 0.0f; }

  for (int kt = 0; kt <= qt; ++kt) {
    __syncthreads();
    {
#pragma unroll
      for (int i = 0; i < 2; ++i)
        GLD16(kbase + (size_t)(b * 1024 + kt * 64 + i * 32 + sr) * RS + sc,
              Ks + i * 2048 + tid * 8);
    }
    {
      const int kvr = lane;
      const int d0 = wave * 16;
      const bf16_t* vr = vbase + (size_t)(b * 1024 + kt * 64 + kvr) * RS + d0;
      bf16x8 v0 = *(const bf16x8*)vr;
      bf16x8 v1 = *(const bf16x8*)(vr + 8);
#pragma unroll
      for (int j = 0; j < 8; ++j) {
        Vt[(d0 + j) * 64 + (kvr ^ (j << 3))]     = v0[j];
        Vt[(d0 + 8 + j) * 64 + (kvr ^ (j << 3))] = v1[j];
      }
    }
    __syncthreads();

    f32x4 s[4] = {};
#pragma unroll
    for (int ni = 0; ni < 4; ++ni) {
      bf16x8 kf0 = *(const bf16x8*)&Ks[SW64(ni * 16 + lrow, koct * 8)];
      bf16x8 kf1 = *(const bf16x8*)&Ks[SW64(ni * 16 + lrow, 32 + koct * 8)];
      s[ni] = mfma16(qf[0], kf0, s[ni]);
      s[ni] = mfma16(qf[1], kf1, s[ni]);
    }

    const int qrow = qt * 64 + wave * 16 + koct * 4;
    float rm[4];
#pragma unroll
    for (int r = 0; r < 4; ++r) rm[r] = -1e30f;
#pragma unroll
    for (int ni = 0; ni < 4; ++ni) {
      const int kcol = kt * 64 + ni * 16 + lrow;
#pragma unroll
      for (int r = 0; r < 4; ++r) {
        float v = s[ni][r] * scale;
        if (kcol > qrow + r) v = -1e30f;
        s[ni][r] = v;
        rm[r] = fmaxf(rm[r], v);
      }
    }
#pragma unroll
    for (int r = 0; r < 4; ++r) RED16_MAX(rm[r]);
    float corr[4], ps[4];
#pragma unroll
    for (int r = 0; r < 4; ++r) {
      const float mn = fmaxf(m_r[r], rm[r]);
      corr[r] = __expf(m_r[r] - mn);
      m_r[r] = mn;
      ps[r] = 0.0f;
    }
#pragma unroll
    for (int ni = 0; ni < 4; ++ni)
#pragma unroll
      for (int r = 0; r < 4; ++r) {
        const float p = __expf(s[ni][r] - m_r[r]);
        s[ni][r] = p;
        ps[r] += p;
      }
#pragma unroll
    for (int r = 0; r < 4; ++r) RED16_SUM(ps[r]);
#pragma unroll
    for (int r = 0; r < 4; ++r) l_r[r] = l_r[r] * corr[r] + ps[r];
#pragma unroll
    for (int ni = 0; ni < 4; ++ni)
#pragma unroll
      for (int r = 0; r < 4; ++r) o[ni][r] *= corr[r];

#pragma unroll
    for (int ni = 0; ni < 4; ++ni)
#pragma unroll
      for (int r = 0; r < 4; ++r) {
        const int prow = koct * 4 + r;
        Ps[wave][prow * 64 + ((ni * 16 + lrow) ^ ((prow & 7) << 3))] =
            (bf16_t)s[ni][r];
      }
    __syncthreads();

    bf16x8 pa0 = *(const bf16x8*)&Ps[wave][SW64(lrow, koct * 8)];
    bf16x8 pa1 = *(const bf16x8*)&Ps[wave][SW64(lrow, 32 + koct * 8)];
#pragma unroll
    for (int ni = 0; ni < 4; ++ni) {
      bf16x8 vf0 = *(const bf16x8*)&Vt[SW64(ni * 16 + lrow, koct * 8)];
      bf16x8 vf1 = *(const bf16x8*)&Vt[SW64(ni * 16 + lrow, 32 + koct * 8)];
      o[ni] = mfma16(pa0, vf0, o[ni]);
      o[ni] = mfma16(pa1, vf1, o[ni]);
    }
  }

#pragma unroll
  for (int r = 0; r < 4; ++r) {
    const float inv = 1.0f / l_r[r];
    const int row = qt * 64 + wave * 16 + koct * 4 + r;
#pragma unroll
    for (int ni = 0; ni < 4; ++ni)
      ab[(size_t)(b * 1024 + row) * 768 + h * 64 + ni * 16 + lrow] =
          (bf16_t)(o[ni][r] * inv);
  }
}

// ---------------------------------------------------------------------------
extern "C" void kernel_launch(void* const* d_in, const int* in_sizes, int n_in,
                              void* d_out, int out_size, void* d_ws, size_t ws_size,
                              hipStream_t stream) {
  (void)in_sizes; (void)n_in; (void)out_size; (void)ws_size;
  const int*   tok   = (const int*)d_in[0];
  const float* emb   = (const float*)d_in[1];
  const float* pe    = (const float*)d_in[2];
  const float* ln1_g = (const float*)d_in[3];
  const float* ln1_b = (const float*)d_in[4];
  const float* wq    = (const float*)d_in[5];
  const float* bq    = (const float*)d_in[6];
  const float* wk    = (const float*)d_in[7];
  const float* bk    = (const float*)d_in[8];
  const float* wv    = (const float*)d_in[9];
  const float* bv    = (const float*)d_in[10];
  const float* wo    = (const float*)d_in[11];
  const float* bo    = (const float*)d_in[12];
  const float* ln2_g = (const float*)d_in[13];
  const float* ln2_b = (const float*)d_in[14];
  const float* w1    = (const float*)d_in[15];
  const float* b1    = (const float*)d_in[16];
  const float* w2    = (const float*)d_in[17];
  const float* b2    = (const float*)d_in[18];
  const float* lnf_g = (const float*)d_in[19];
  const float* lnf_b = (const float*)d_in[20];
  const float* w_out = (const float*)d_in[21];
  float* out = (float*)d_out;

  char* ws = (char*)d_ws;
  size_t off = 0;
  auto alloc = [&](size_t bytes) -> void* {
    void* p = ws + off;
    off += (bytes + 255) & ~(size_t)255;
    return p;
  };
  float*  xf      = (float*)alloc(4096ull * 768 * 4);
  bf16_t* hb      = (bf16_t*)alloc(4096ull * 768 * 2);
  bf16_t* qkvb    = (bf16_t*)alloc(4096ull * 2304 * 2);
  bf16_t* ab      = (bf16_t*)alloc(4096ull * 768 * 2);
  bf16_t* fb      = (bf16_t*)alloc(4096ull * 3072 * 2);
  float*  qkvbias = (float*)alloc(4ull * 2304 * 4);
  bf16_t* wqkvT   = (bf16_t*)alloc(4ull * 2304 * 768 * 2);
  bf16_t* woT     = (bf16_t*)alloc(4ull * 768 * 768 * 2);
  bf16_t* w1T     = (bf16_t*)alloc(4ull * 3072 * 768 * 2);
  bf16_t* w2T     = (bf16_t*)alloc(4ull * 768 * 3072 * 2);
  bf16_t* woutT   = (bf16_t*)alloc(32000ull * 768 * 2);

  // ---- weight convert+transpose (batched over layers via gridDim.z) ----
  tconv_k<<<dim3(24, 24, 4), 256, 0, stream>>>(wq, wqkvT, 768, 768,
      768ull * 768, 2304ull * 768);
  tconv_k<<<dim3(24, 24, 4), 256, 0, stream>>>(wk, wqkvT + 768ull * 768, 768, 768,
      768ull * 768, 2304ull * 768);
  tconv_k<<<dim3(24, 24, 4), 256, 0, stream>>>(wv, wqkvT + 2ull * 768 * 768, 768, 768,
      768ull * 768, 2304ull * 768);
  tconv_k<<<dim3(24, 24, 4), 256, 0, stream>>>(wo, woT, 768, 768,
      768ull * 768, 768ull * 768);
  tconv_k<<<dim3(96, 24, 4), 256, 0, stream>>>(w1, w1T, 768, 3072,
      768ull * 3072, 3072ull * 768);
  tconv_k<<<dim3(24, 96, 4), 256, 0, stream>>>(w2, w2T, 3072, 768,
      3072ull * 768, 768ull * 3072);
  tconv_k<<<dim3(1000, 24, 1), 256, 0, stream>>>(w_out, woutT, 768, 32000, 0, 0);
  qkvbias_k<<<4, 256, 0, stream>>>(bq, bk, bv, qkvbias);

  // ---- forward ----
  embed_k<<<4096, 256, 0, stream>>>(tok, emb, pe, xf);

  const size_t SMEM8P = 131072;      // 128 KiB (gemm8p)
  const size_t SMEMS  = 3 * 24576;   // 72 KiB (gemmS)
  for (int l = 0; l < 4; ++l) {
    ln_k<<<4096, 256, 0, stream>>>(xf, ln1_g + l * 768, ln1_b + l * 768, hb);
    gemm8p<true, false, false, false, 0><<<16 * 9, 512, SMEM8P, stream>>>(
        hb, wqkvT + (size_t)l * 2304 * 768, qkvbias + l * 2304,
        nullptr, qkvb, 4096, 2304, 768);
    attn_k<<<dim3(16, 12, 4), 256, 0, stream>>>(qkvb, ab);
    gemmS<true, false, true, true><<<64 * 6, 256, SMEMS, stream>>>(
        ab, woT + (size_t)l * 768 * 768, bo + l * 768,
        xf, xf, nullptr, 4096, 768, 768);
    ln_k<<<4096, 256, 0, stream>>>(xf, ln2_g + l * 768, ln2_b + l * 768, hb);
    gemm8p<true, true, false, false, 0><<<16 * 12, 512, SMEM8P, stream>>>(
        hb, w1T + (size_t)l * 3072 * 768, b1 + l * 3072,
        nullptr, fb, 4096, 3072, 768);
    gemmS<true, false, true, true><<<64 * 6, 256, SMEMS, stream>>>(
        fb, w2T + (size_t)l * 768 * 3072, b2 + l * 768,
        xf, xf, nullptr, 4096, 768, 3072);
  }
  ln_k<<<4096, 256, 0, stream>>>(xf, lnf_g, lnf_b, hb);
  gemm8p<false, false, true, true, 5><<<16 * 125, 512, SMEM8P, stream>>>(
      hb, woutT, nullptr, out, nullptr, 4096, 32000, 768);
}